// Round 3
// baseline (10924.628 us; speedup 1.0000x reference)
//
#include <hip/hip_runtime.h>

#define DIM 64
#define DIM4 (DIM / 4)
#define BROWS 128          // destination rows per bucket
#define LROW 68            // padded LDS row stride (floats); 68*4=272 B, 16B-aligned
#define MAXNB 2048
#define TILE 16384         // edges per binning block

// ---------- shared small kernels ----------

__global__ void init_concat(const float4* __restrict__ ue, const float4* __restrict__ ie,
                            float4* __restrict__ cur, long nU4, long total4) {
    long i = (long)blockIdx.x * blockDim.x + threadIdx.x;
    if (i >= total4) return;
    cur[i] = (i < nU4) ? ue[i] : ie[i - nU4];
}

__global__ void gather_accum(const int* __restrict__ idx, int offset,
                             const float* __restrict__ x, float* __restrict__ acc, int B) {
    long gid = (long)blockIdx.x * blockDim.x + threadIdx.x;
    int lane = (int)(gid & 15);
    long b = gid >> 4;
    if (b >= B) return;
    long node = (long)idx[b] + offset;
    float4 r = ((const float4*)(x + node * DIM))[lane];
    float4* a = (float4*)(acc + b * DIM) + lane;
    float4 av = *a;
    av.x += r.x; av.y += r.y; av.z += r.z; av.w += r.w;
    *a = av;
}

__global__ void dot_pairs(const float* __restrict__ aU, const float* __restrict__ aI,
                          float* __restrict__ out, int B) {
    long gid = (long)blockIdx.x * blockDim.x + threadIdx.x;
    int lane = (int)(gid & 15);
    long b = gid >> 4;
    if (b >= B) return;
    float4 u = ((const float4*)(aU + b * DIM))[lane];
    float4 v = ((const float4*)(aI + b * DIM))[lane];
    float s = u.x * v.x + u.y * v.y + u.z * v.z + u.w * v.w;
    s += __shfl_xor(s, 1);
    s += __shfl_xor(s, 2);
    s += __shfl_xor(s, 4);
    s += __shfl_xor(s, 8);
    if (lane == 0) out[b] = s * (1.0f / 16.0f);
}

// ---------- scan pipeline (generic over n entries) ----------

__global__ void scan_block(const int* __restrict__ cnt, int* __restrict__ out,
                           int* __restrict__ blockSums, int n) {
    __shared__ int tmp[256];
    int i = blockIdx.x * 256 + threadIdx.x;
    int v = (i < n) ? cnt[i] : 0;
    tmp[threadIdx.x] = v;
    __syncthreads();
    for (int off = 1; off < 256; off <<= 1) {
        int t = (threadIdx.x >= off) ? tmp[threadIdx.x - off] : 0;
        __syncthreads();
        tmp[threadIdx.x] += t;
        __syncthreads();
    }
    if (i < n) out[i] = tmp[threadIdx.x];
    if (threadIdx.x == 255) blockSums[blockIdx.x] = tmp[255];
}

__global__ void scan_sums(int* __restrict__ blockSums, int nb) {
    __shared__ int tmp[1024];
    int i = threadIdx.x;
    tmp[i] = (i < nb) ? blockSums[i] : 0;
    __syncthreads();
    for (int off = 1; off < 1024; off <<= 1) {
        int t = (i >= off) ? tmp[i - off] : 0;
        __syncthreads();
        tmp[i] += t;
        __syncthreads();
    }
    if (i < nb) blockSums[i] = (i > 0) ? tmp[i - 1] : 0;
}

__global__ void scan_finalize(const int* __restrict__ cnt, const int* __restrict__ blockSums,
                              int* __restrict__ rowptr, int* __restrict__ cursor, int n) {
    int i = blockIdx.x * 256 + threadIdx.x;
    if (i >= n) return;
    int inc = rowptr[i + 1] + blockSums[blockIdx.x];
    rowptr[i + 1] = inc;
    cursor[i] = inc - cnt[i];
    if (i == 0) rowptr[0] = 0;
}

// ---------- bucket binning ----------

__global__ void bucket_hist(const int* __restrict__ edst, int* __restrict__ cnt,
                            int E, int NB) {
    __shared__ int h[MAXNB];
    for (int i = threadIdx.x; i < NB; i += 256) h[i] = 0;
    __syncthreads();
    int base = blockIdx.x * TILE;
    int end = base + TILE; if (end > E) end = E;
    for (int e = base + threadIdx.x; e < end; e += 256)
        atomicAdd(&h[edst[e] >> 7], 1);
    __syncthreads();
    for (int i = threadIdx.x; i < NB; i += 256)
        if (h[i]) atomicAdd(&cnt[i], h[i]);
}

__global__ void bucket_scatter(const int* __restrict__ esrc, const int* __restrict__ edst,
                               const float* __restrict__ evals, int* __restrict__ cursor,
                               int2* __restrict__ tmp, int E, int NB) {
    __shared__ int h[MAXNB];   // histogram, then per-bucket rank counters
    __shared__ int cb[MAXNB];  // per-bucket chunk base for this block
    for (int i = threadIdx.x; i < NB; i += 256) h[i] = 0;
    __syncthreads();
    int base = blockIdx.x * TILE;
    int end = base + TILE; if (end > E) end = E;
    for (int e = base + threadIdx.x; e < end; e += 256)
        atomicAdd(&h[edst[e] >> 7], 1);
    __syncthreads();
    for (int i = threadIdx.x; i < NB; i += 256) {
        int c = h[i];
        if (c) cb[i] = atomicAdd(&cursor[i], c);
        h[i] = 0;   // reset for rank pass
    }
    __syncthreads();
    for (int e = base + threadIdx.x; e < end; e += 256) {
        int d = edst[e];
        int b = d >> 7;
        int r = atomicAdd(&h[b], 1);
        int pos = cb[b] + r;
        tmp[pos] = make_int2(esrc[e] | ((d & 127) << 18), __float_as_int(evals[e]));
    }
}

// ---------- LDS-accumulating pull: one block per 128-row bucket ----------

__global__ void spmm_pull_lds(const int* __restrict__ bptr, const int2* __restrict__ tmp,
                              const float* __restrict__ x, float* __restrict__ y, int N) {
    __shared__ float tile[BROWS * LROW];  // 34816 B
    for (int i = threadIdx.x; i < BROWS * LROW; i += 256) tile[i] = 0.f;
    __syncthreads();
    int b = blockIdx.x;
    int beg = bptr[b], end = bptr[b + 1];
    int g = threadIdx.x >> 4;
    int lane = threadIdx.x & 15;
    int e = beg + g;
    for (; e + 16 < end; e += 32) {
        int2 p0 = tmp[e];
        int2 p1 = tmp[e + 16];
        int s0 = p0.x & 0x3FFFF, d0 = p0.x >> 18;
        int s1 = p1.x & 0x3FFFF, d1 = p1.x >> 18;
        float v0 = __int_as_float(p0.y);
        float v1 = __int_as_float(p1.y);
        float4 x0 = ((const float4*)(x + (long)s0 * DIM))[lane];
        float4 x1 = ((const float4*)(x + (long)s1 * DIM))[lane];
        float* t0 = &tile[d0 * LROW + lane * 4];
        atomicAdd(t0 + 0, v0 * x0.x); atomicAdd(t0 + 1, v0 * x0.y);
        atomicAdd(t0 + 2, v0 * x0.z); atomicAdd(t0 + 3, v0 * x0.w);
        float* t1 = &tile[d1 * LROW + lane * 4];
        atomicAdd(t1 + 0, v1 * x1.x); atomicAdd(t1 + 1, v1 * x1.y);
        atomicAdd(t1 + 2, v1 * x1.z); atomicAdd(t1 + 3, v1 * x1.w);
    }
    if (e < end) {
        int2 p = tmp[e];
        int s = p.x & 0x3FFFF, d = p.x >> 18;
        float v = __int_as_float(p.y);
        float4 xr = ((const float4*)(x + (long)s * DIM))[lane];
        float* t = &tile[d * LROW + lane * 4];
        atomicAdd(t + 0, v * xr.x); atomicAdd(t + 1, v * xr.y);
        atomicAdd(t + 2, v * xr.z); atomicAdd(t + 3, v * xr.w);
    }
    __syncthreads();
    int rbase = b * BROWS;
    for (int i = threadIdx.x; i < BROWS * 16; i += 256) {
        int lr = i >> 4, li = i & 15;
        int r = rbase + lr;
        if (r < N) {
            float4 vv = *(const float4*)&tile[lr * LROW + li * 4];
            ((float4*)(y + (long)r * DIM))[li] = vv;
        }
    }
}

// ---------- fallback (atomic scatter) ----------

__global__ void spmm_scatter(const int* __restrict__ src, const int* __restrict__ dst,
                             const float* __restrict__ vals, const float* __restrict__ x,
                             float* __restrict__ y, int E) {
    long gid = (long)blockIdx.x * blockDim.x + threadIdx.x;
    int lane = (int)(gid & 15);
    long e = gid >> 4;
    if (e >= E) return;
    int s = src[e];
    int d = dst[e];
    float v = vals[e];
    float4 r = ((const float4*)(x + (long)s * DIM))[lane];
    float* yp = y + (long)d * DIM + lane * 4;
    atomicAdd(yp + 0, v * r.x);
    atomicAdd(yp + 1, v * r.y);
    atomicAdd(yp + 2, v * r.z);
    atomicAdd(yp + 3, v * r.w);
}

extern "C" void kernel_launch(void* const* d_in, const int* in_sizes, int n_in,
                              void* d_out, int out_size, void* d_ws, size_t ws_size,
                              hipStream_t stream) {
    const int*   users = (const int*)d_in[0];
    const int*   items = (const int*)d_in[1];
    const int*   esrc  = (const int*)d_in[2];
    const int*   edst  = (const int*)d_in[3];
    const float* evals = (const float*)d_in[4];
    const float* uemb  = (const float*)d_in[5];
    const float* iemb  = (const float*)d_in[6];

    const int B  = in_sizes[0];
    const int E  = in_sizes[2];
    const int nU = in_sizes[5] / DIM;
    const int nI = in_sizes[6] / DIM;
    const int N  = nU + nI;
    const int NB = (N + BROWS - 1) / BROWS;   // buckets of 128 rows

    const int T = 256;
    float* gout = (float*)d_out;

    // workspace layout (same footprint as round 2)
    size_t need = ((size_t)2 * N * DIM + (size_t)2 * B * DIM) * 4
                + (size_t)E * 8
                + ((size_t)3 * N + 2 + 1024) * 4;
    float* cur  = (float*)d_ws;
    float* nxt  = cur  + (size_t)N * DIM;
    float* accU = nxt  + (size_t)N * DIM;
    float* accI = accU + (size_t)B * DIM;
    int2*  tmp  = (int2*)(accI + (size_t)B * DIM);
    int*   cnt    = (int*)(tmp + (size_t)E);
    int*   bptr   = cnt + N;          // NB+1 used
    int*   cursor = bptr + (N + 1);   // NB used
    int*   blockSums = cursor + N;

    long total4 = (long)N * DIM4;
    long nU4    = (long)nU * DIM4;
    int gb = (int)(((long)B * 16 + T - 1) / T);

    hipMemsetAsync(accU, 0, (size_t)B * DIM * 2 * sizeof(float), stream);
    init_concat<<<(int)((total4 + T - 1) / T), T, 0, stream>>>(
        (const float4*)uemb, (const float4*)iemb, (float4*)cur, nU4, total4);
    gather_accum<<<gb, T, 0, stream>>>(users, 0,  cur, accU, B);
    gather_accum<<<gb, T, 0, stream>>>(items, nU, cur, accI, B);

    if (ws_size >= need && NB <= MAXNB) {
        // ---- coarse binning: bucket = dst >> 7 ----
        int tb = (E + TILE - 1) / TILE;
        hipMemsetAsync(cnt, 0, (size_t)NB * sizeof(int), stream);
        bucket_hist<<<tb, T, 0, stream>>>(edst, cnt, E, NB);
        int nb = (NB + 255) / 256;
        scan_block<<<nb, 256, 0, stream>>>(cnt, bptr + 1, blockSums, NB);
        scan_sums<<<1, 1024, 0, stream>>>(blockSums, nb);
        scan_finalize<<<nb, 256, 0, stream>>>(cnt, blockSums, bptr, cursor, NB);
        bucket_scatter<<<tb, T, 0, stream>>>(esrc, edst, evals, cursor, tmp, E, NB);

        for (int l = 0; l < 3; ++l) {
            spmm_pull_lds<<<NB, T, 0, stream>>>(bptr, tmp, cur, nxt, N);
            gather_accum<<<gb, T, 0, stream>>>(users, 0,  nxt, accU, B);
            gather_accum<<<gb, T, 0, stream>>>(items, nU, nxt, accI, B);
            float* t = cur; cur = nxt; nxt = t;
        }
    } else {
        int sb = (int)(((long)E * 16 + T - 1) / T);
        for (int l = 0; l < 3; ++l) {
            hipMemsetAsync(nxt, 0, (size_t)N * DIM * sizeof(float), stream);
            spmm_scatter<<<sb, T, 0, stream>>>(esrc, edst, evals, cur, nxt, E);
            gather_accum<<<gb, T, 0, stream>>>(users, 0,  nxt, accU, B);
            gather_accum<<<gb, T, 0, stream>>>(items, nU, nxt, accI, B);
            float* t = cur; cur = nxt; nxt = t;
        }
    }

    dot_pairs<<<(int)(((long)B * 16 + T - 1) / T), T, 0, stream>>>(accU, accI, gout, B);
}

// Round 4
// 1431.171 us; speedup vs baseline: 7.6333x; 7.6333x over previous
//
#include <hip/hip_runtime.h>

#define DIM 64
#define BROWS 128          // rows per bucket
#define MAXNB 2048
#define TILE 16384         // edges per binning block

typedef unsigned short bf16_t;

__device__ __forceinline__ float bf2f(unsigned short h) {
    return __uint_as_float(((unsigned)h) << 16);
}
__device__ __forceinline__ unsigned short f2bf(float f) {
    unsigned u = __float_as_uint(f);
    u += 0x7FFFu + ((u >> 16) & 1u);           // round-to-nearest-even
    return (unsigned short)(u >> 16);
}

// ---------- build bf16 node matrix from fp32 embeddings ----------
__global__ void build_xb(const float4* __restrict__ ue, const float4* __restrict__ ie,
                         ushort4* __restrict__ xb, long nU4, long total4) {
    long i = (long)blockIdx.x * blockDim.x + threadIdx.x;
    if (i >= total4) return;
    float4 v = (i < nU4) ? ue[i] : ie[i - nU4];
    ushort4 o;
    o.x = f2bf(v.x); o.y = f2bf(v.y); o.z = f2bf(v.z); o.w = f2bf(v.w);
    xb[i] = o;
}

// ---------- layer-0 gather (fp32 source) ----------
__global__ void gather_accum_f32(const int* __restrict__ idx, const float* __restrict__ x,
                                 float* __restrict__ acc, int B) {
    long gid = (long)blockIdx.x * blockDim.x + threadIdx.x;
    int lane = (int)(gid & 15);
    long b = gid >> 4;
    if (b >= B) return;
    long node = (long)idx[b];
    float4 r = ((const float4*)(x + node * DIM))[lane];
    float4* a = (float4*)(acc + b * DIM) + lane;
    float4 av = *a;
    av.x += r.x; av.y += r.y; av.z += r.z; av.w += r.w;
    *a = av;
}

// ---------- layer 1..3 gather (bf16 source) ----------
__global__ void gather_accum_bf16(const int* __restrict__ idx, int offset,
                                  const bf16_t* __restrict__ xb, float* __restrict__ acc, int B) {
    long gid = (long)blockIdx.x * blockDim.x + threadIdx.x;
    int lane = (int)(gid & 15);
    long b = gid >> 4;
    if (b >= B) return;
    long node = (long)idx[b] + offset;
    ushort4 r = *(const ushort4*)(xb + node * DIM + lane * 4);
    float4* a = (float4*)(acc + b * DIM) + lane;
    float4 av = *a;
    av.x += bf2f(r.x); av.y += bf2f(r.y); av.z += bf2f(r.z); av.w += bf2f(r.w);
    *a = av;
}

__global__ void dot_pairs(const float* __restrict__ aU, const float* __restrict__ aI,
                          float* __restrict__ out, int B) {
    long gid = (long)blockIdx.x * blockDim.x + threadIdx.x;
    int lane = (int)(gid & 15);
    long b = gid >> 4;
    if (b >= B) return;
    float4 u = ((const float4*)(aU + b * DIM))[lane];
    float4 v = ((const float4*)(aI + b * DIM))[lane];
    float s = u.x * v.x + u.y * v.y + u.z * v.z + u.w * v.w;
    s += __shfl_xor(s, 1);
    s += __shfl_xor(s, 2);
    s += __shfl_xor(s, 4);
    s += __shfl_xor(s, 8);
    if (lane == 0) out[b] = s * (1.0f / 16.0f);
}

// ---------- degree count + scan ----------
__global__ void count_deg(const int* __restrict__ dst, int* __restrict__ cnt, int E) {
    int e = blockIdx.x * blockDim.x + threadIdx.x;
    if (e >= E) return;
    atomicAdd(&cnt[dst[e]], 1);
}

__global__ void scan_block(const int* __restrict__ cnt, int* __restrict__ out,
                           int* __restrict__ blockSums, int n) {
    __shared__ int tmp[256];
    int i = blockIdx.x * 256 + threadIdx.x;
    int v = (i < n) ? cnt[i] : 0;
    tmp[threadIdx.x] = v;
    __syncthreads();
    for (int off = 1; off < 256; off <<= 1) {
        int t = (threadIdx.x >= off) ? tmp[threadIdx.x - off] : 0;
        __syncthreads();
        tmp[threadIdx.x] += t;
        __syncthreads();
    }
    if (i < n) out[i] = tmp[threadIdx.x];
    if (threadIdx.x == 255) blockSums[blockIdx.x] = tmp[255];
}

__global__ void scan_sums(int* __restrict__ blockSums, int nb) {
    __shared__ int tmp[1024];
    int i = threadIdx.x;
    tmp[i] = (i < nb) ? blockSums[i] : 0;
    __syncthreads();
    for (int off = 1; off < 1024; off <<= 1) {
        int t = (i >= off) ? tmp[i - off] : 0;
        __syncthreads();
        tmp[i] += t;
        __syncthreads();
    }
    if (i < nb) blockSums[i] = (i > 0) ? tmp[i - 1] : 0;
}

__global__ void scan_finalize(const int* __restrict__ cnt, const int* __restrict__ blockSums,
                              int* __restrict__ rowptr, int* __restrict__ cursor, int n) {
    int i = blockIdx.x * 256 + threadIdx.x;
    if (i >= n) return;
    int inc = rowptr[i + 1] + blockSums[blockIdx.x];
    rowptr[i + 1] = inc;
    cursor[i] = inc - cnt[i];
    if (i == 0) rowptr[0] = 0;
}

__global__ void init_bcur(const int* __restrict__ rowptr, int* __restrict__ bcur, int NB, int N) {
    int b = blockIdx.x * blockDim.x + threadIdx.x;
    if (b > NB) return;
    int r = b * BROWS; if (r > N) r = N;
    bcur[b] = rowptr[r];
}

// ---------- bucket binning: group edges by 128-row destination bucket ----------
__global__ void bucket_scatter(const int* __restrict__ esrc, const int* __restrict__ edst,
                               const float* __restrict__ evals, int* __restrict__ bcur,
                               int2* __restrict__ tmp, int E, int NB) {
    __shared__ int h[MAXNB];   // histogram, then per-bucket rank counters
    __shared__ int cb[MAXNB];  // per-bucket chunk base for this block
    for (int i = threadIdx.x; i < NB; i += 256) h[i] = 0;
    __syncthreads();
    int base = blockIdx.x * TILE;
    int end = base + TILE; if (end > E) end = E;
    for (int e = base + threadIdx.x; e < end; e += 256)
        atomicAdd(&h[edst[e] >> 7], 1);
    __syncthreads();
    for (int i = threadIdx.x; i < NB; i += 256) {
        int c = h[i];
        if (c) cb[i] = atomicAdd(&bcur[i], c);
        h[i] = 0;
    }
    __syncthreads();
    for (int e = base + threadIdx.x; e < end; e += 256) {
        int d = edst[e];
        int b = d >> 7;
        int r = atomicAdd(&h[b], 1);
        tmp[cb[b] + r] = make_int2(esrc[e] | ((d & 127) << 18), __float_as_int(evals[e]));
    }
}

// ---------- finalize CSR: rank-sort each bucket's edges into node order ----------
__global__ void csr_from_buckets(const int* __restrict__ rowptr, const int2* __restrict__ tmp,
                                 int2* __restrict__ pairs, int N) {
    __shared__ int lcnt[BROWS];
    int b = blockIdx.x;
    int rbase = b * BROWS;
    int rend = rbase + BROWS; if (rend > N) rend = N;
    int beg = rowptr[rbase], end = rowptr[rend];
    if (threadIdx.x < BROWS) lcnt[threadIdx.x] = 0;
    __syncthreads();
    for (int e = beg + threadIdx.x; e < end; e += 256) {
        int2 p = tmp[e];
        int dl = p.x >> 18;
        int r = atomicAdd(&lcnt[dl], 1);
        pairs[rowptr[rbase + dl] + r] = make_int2(p.x & 0x3FFFF, p.y);
    }
}

// ---------- fallback CSR fill (direct atomic scatter, higher write amp) ----------
__global__ void csr_fill(const int* __restrict__ src, const int* __restrict__ dst,
                         const float* __restrict__ vals, int* __restrict__ cursor,
                         int2* __restrict__ pairs, int E) {
    int e = blockIdx.x * blockDim.x + threadIdx.x;
    if (e >= E) return;
    int d = dst[e];
    int pos = atomicAdd(&cursor[d], 1);
    pairs[pos] = make_int2(src[e], __float_as_int(vals[e]));
}

// ---------- pull-mode SpMM, bf16 rows: one 16-lane group per destination row ----------
__global__ void spmm_pull_bf16(const int* __restrict__ rowptr, const int2* __restrict__ pairs,
                               const bf16_t* __restrict__ xb, bf16_t* __restrict__ yb, int Nrows) {
    long gid = (long)blockIdx.x * blockDim.x + threadIdx.x;
    int lane = (int)(gid & 15);
    long r = gid >> 4;
    if (r >= Nrows) return;
    int beg = rowptr[r];
    int end = rowptr[r + 1];
    float4 acc = make_float4(0.f, 0.f, 0.f, 0.f);
    int e = beg;
    for (; e + 3 < end; e += 4) {
        int2 p0 = pairs[e];
        int2 p1 = pairs[e + 1];
        int2 p2 = pairs[e + 2];
        int2 p3 = pairs[e + 3];
        ushort4 a0 = *(const ushort4*)(xb + (long)p0.x * DIM + lane * 4);
        ushort4 a1 = *(const ushort4*)(xb + (long)p1.x * DIM + lane * 4);
        ushort4 a2 = *(const ushort4*)(xb + (long)p2.x * DIM + lane * 4);
        ushort4 a3 = *(const ushort4*)(xb + (long)p3.x * DIM + lane * 4);
        float v0 = __int_as_float(p0.y), v1 = __int_as_float(p1.y);
        float v2 = __int_as_float(p2.y), v3 = __int_as_float(p3.y);
        acc.x += v0 * bf2f(a0.x) + v1 * bf2f(a1.x) + v2 * bf2f(a2.x) + v3 * bf2f(a3.x);
        acc.y += v0 * bf2f(a0.y) + v1 * bf2f(a1.y) + v2 * bf2f(a2.y) + v3 * bf2f(a3.y);
        acc.z += v0 * bf2f(a0.z) + v1 * bf2f(a1.z) + v2 * bf2f(a2.z) + v3 * bf2f(a3.z);
        acc.w += v0 * bf2f(a0.w) + v1 * bf2f(a1.w) + v2 * bf2f(a2.w) + v3 * bf2f(a3.w);
    }
    for (; e < end; ++e) {
        int2 p = pairs[e];
        float v = __int_as_float(p.y);
        ushort4 a = *(const ushort4*)(xb + (long)p.x * DIM + lane * 4);
        acc.x += v * bf2f(a.x); acc.y += v * bf2f(a.y);
        acc.z += v * bf2f(a.z); acc.w += v * bf2f(a.w);
    }
    ushort4 o;
    o.x = f2bf(acc.x); o.y = f2bf(acc.y); o.z = f2bf(acc.z); o.w = f2bf(acc.w);
    *(ushort4*)(yb + r * DIM + lane * 4) = o;
}

extern "C" void kernel_launch(void* const* d_in, const int* in_sizes, int n_in,
                              void* d_out, int out_size, void* d_ws, size_t ws_size,
                              hipStream_t stream) {
    const int*   users = (const int*)d_in[0];
    const int*   items = (const int*)d_in[1];
    const int*   esrc  = (const int*)d_in[2];
    const int*   edst  = (const int*)d_in[3];
    const float* evals = (const float*)d_in[4];
    const float* uemb  = (const float*)d_in[5];
    const float* iemb  = (const float*)d_in[6];

    const int B  = in_sizes[0];
    const int E  = in_sizes[2];
    const int nU = in_sizes[5] / DIM;
    const int nI = in_sizes[6] / DIM;
    const int N  = nU + nI;
    const int NB = (N + BROWS - 1) / BROWS;

    const int T = 256;
    float* gout = (float*)d_out;

    // ---- workspace layout (tmp last so fallback path needs less) ----
    char* p = (char*)d_ws;
    float*  accU  = (float*)p;          p += (size_t)B * DIM * 4;
    float*  accI  = (float*)p;          p += (size_t)B * DIM * 4;
    bf16_t* xbCur = (bf16_t*)p;         p += (size_t)N * DIM * 2;
    bf16_t* xbNxt = (bf16_t*)p;         p += (size_t)N * DIM * 2;
    int*    cnt    = (int*)p;           p += (size_t)N * 4;
    int*    rowptr = (int*)p;           p += (size_t)(N + 1) * 4;
    int*    cursor = (int*)p;           p += (size_t)N * 4;
    int*    bcur   = (int*)p;           p += (size_t)(NB + 1) * 4;
    int*    blockSums = (int*)p;        p += 1024 * 4;
    p = (char*)(((size_t)p + 15) & ~(size_t)15);
    int2*   pairs  = (int2*)p;          p += (size_t)E * 8;
    size_t need_fb = (size_t)(p - (char*)d_ws);
    int2*   tmp    = (int2*)p;          p += (size_t)E * 8;
    size_t need_fast = (size_t)(p - (char*)d_ws);

    long total4 = (long)N * (DIM / 4);
    long nU4    = (long)nU * (DIM / 4);
    int gb = (int)(((long)B * 16 + T - 1) / T);
    int eb = (E + T - 1) / T;
    int nbN = (N + 255) / 256;

    // layer-0 accumulators straight from fp32 embeddings
    hipMemsetAsync(accU, 0, (size_t)B * DIM * 2 * sizeof(float), stream);
    gather_accum_f32<<<gb, T, 0, stream>>>(users, uemb, accU, B);
    gather_accum_f32<<<gb, T, 0, stream>>>(items, iemb, accI, B);

    // bf16 node matrix
    build_xb<<<(int)((total4 + T - 1) / T), T, 0, stream>>>(
        (const float4*)uemb, (const float4*)iemb, (ushort4*)xbCur, nU4, total4);

    // ---- CSR build ----
    hipMemsetAsync(cnt, 0, (size_t)N * sizeof(int), stream);
    count_deg<<<eb, T, 0, stream>>>(edst, cnt, E);
    scan_block<<<nbN, 256, 0, stream>>>(cnt, rowptr + 1, blockSums, N);
    scan_sums<<<1, 1024, 0, stream>>>(blockSums, nbN);
    scan_finalize<<<nbN, 256, 0, stream>>>(cnt, blockSums, rowptr, cursor, N);

    if (ws_size >= need_fast && NB <= MAXNB) {
        // low-write-amp two-phase: bucket-group then rank-sort per bucket
        init_bcur<<<(NB + T) / T + 1, T, 0, stream>>>(rowptr, bcur, NB, N);
        int tb = (E + TILE - 1) / TILE;
        bucket_scatter<<<tb, T, 0, stream>>>(esrc, edst, evals, bcur, tmp, E, NB);
        csr_from_buckets<<<NB, T, 0, stream>>>(rowptr, tmp, pairs, N);
    } else {
        // direct atomic fill (correct, more write amplification)
        csr_fill<<<eb, T, 0, stream>>>(esrc, edst, evals, cursor, pairs, E);
    }

    // ---- 3 propagation layers, bf16 storage, fp32 accumulation ----
    int pb = (int)(((long)N * 16 + T - 1) / T);
    for (int l = 0; l < 3; ++l) {
        spmm_pull_bf16<<<pb, T, 0, stream>>>(rowptr, pairs, xbCur, xbNxt, N);
        gather_accum_bf16<<<gb, T, 0, stream>>>(users, 0,  xbNxt, accU, B);
        gather_accum_bf16<<<gb, T, 0, stream>>>(items, nU, xbNxt, accI, B);
        bf16_t* t = xbCur; xbCur = xbNxt; xbNxt = t;
    }

    dot_pairs<<<gb, T, 0, stream>>>(accU, accI, gout, B);
}

// Round 5
// 1104.418 us; speedup vs baseline: 9.8917x; 1.2959x over previous
//
#include <hip/hip_runtime.h>

#define DIM 64
#define BROWS 128          // rows per bucket
#define MAXNB 2048
#define TILE 16384         // edges per binning block

typedef unsigned short bf16_t;

__device__ __forceinline__ float bf2f(unsigned short h) {
    return __uint_as_float(((unsigned)h) << 16);
}
__device__ __forceinline__ unsigned short f2bf(float f) {
    unsigned u = __float_as_uint(f);
    u += 0x7FFFu + ((u >> 16) & 1u);           // round-to-nearest-even
    return (unsigned short)(u >> 16);
}

// ---------- build bf16 node matrix from fp32 embeddings ----------
__global__ void build_xb(const float4* __restrict__ ue, const float4* __restrict__ ie,
                         ushort4* __restrict__ xb, long nU4, long total4) {
    long i = (long)blockIdx.x * blockDim.x + threadIdx.x;
    if (i >= total4) return;
    float4 v = (i < nU4) ? ue[i] : ie[i - nU4];
    ushort4 o;
    o.x = f2bf(v.x); o.y = f2bf(v.y); o.z = f2bf(v.z); o.w = f2bf(v.w);
    xb[i] = o;
}

// ---------- layer-0 gather (fp32 source) ----------
__global__ void gather_accum_f32(const int* __restrict__ idx, const float* __restrict__ x,
                                 float* __restrict__ acc, int B) {
    long gid = (long)blockIdx.x * blockDim.x + threadIdx.x;
    int lane = (int)(gid & 15);
    long b = gid >> 4;
    if (b >= B) return;
    long node = (long)idx[b];
    float4 r = ((const float4*)(x + node * DIM))[lane];
    float4* a = (float4*)(acc + b * DIM) + lane;
    float4 av = *a;
    av.x += r.x; av.y += r.y; av.z += r.z; av.w += r.w;
    *a = av;
}

// ---------- layer 1..3 gather (bf16 source) ----------
__global__ void gather_accum_bf16(const int* __restrict__ idx, int offset,
                                  const bf16_t* __restrict__ xb, float* __restrict__ acc, int B) {
    long gid = (long)blockIdx.x * blockDim.x + threadIdx.x;
    int lane = (int)(gid & 15);
    long b = gid >> 4;
    if (b >= B) return;
    long node = (long)idx[b] + offset;
    ushort4 r = *(const ushort4*)(xb + node * DIM + lane * 4);
    float4* a = (float4*)(acc + b * DIM) + lane;
    float4 av = *a;
    av.x += bf2f(r.x); av.y += bf2f(r.y); av.z += bf2f(r.z); av.w += bf2f(r.w);
    *a = av;
}

__global__ void dot_pairs(const float* __restrict__ aU, const float* __restrict__ aI,
                          float* __restrict__ out, int B) {
    long gid = (long)blockIdx.x * blockDim.x + threadIdx.x;
    int lane = (int)(gid & 15);
    long b = gid >> 4;
    if (b >= B) return;
    float4 u = ((const float4*)(aU + b * DIM))[lane];
    float4 v = ((const float4*)(aI + b * DIM))[lane];
    float s = u.x * v.x + u.y * v.y + u.z * v.z + u.w * v.w;
    s += __shfl_xor(s, 1);
    s += __shfl_xor(s, 2);
    s += __shfl_xor(s, 4);
    s += __shfl_xor(s, 8);
    if (lane == 0) out[b] = s * (1.0f / 16.0f);
}

// ---------- bucket histogram (LDS-aggregated; NB counters only) ----------
__global__ void bucket_hist(const int* __restrict__ edst, int* __restrict__ bcnt,
                            int E, int NB) {
    __shared__ int h[MAXNB];
    for (int i = threadIdx.x; i < NB; i += 256) h[i] = 0;
    __syncthreads();
    int base = blockIdx.x * TILE;
    int end = base + TILE; if (end > E) end = E;
    for (int e = base + threadIdx.x; e < end; e += 256)
        atomicAdd(&h[edst[e] >> 7], 1);
    __syncthreads();
    for (int i = threadIdx.x; i < NB; i += 256)
        if (h[i]) atomicAdd(&bcnt[i], h[i]);
}

// ---------- generic scan pipeline ----------
__global__ void scan_block(const int* __restrict__ cnt, int* __restrict__ out,
                           int* __restrict__ blockSums, int n) {
    __shared__ int tmp[256];
    int i = blockIdx.x * 256 + threadIdx.x;
    int v = (i < n) ? cnt[i] : 0;
    tmp[threadIdx.x] = v;
    __syncthreads();
    for (int off = 1; off < 256; off <<= 1) {
        int t = (threadIdx.x >= off) ? tmp[threadIdx.x - off] : 0;
        __syncthreads();
        tmp[threadIdx.x] += t;
        __syncthreads();
    }
    if (i < n) out[i] = tmp[threadIdx.x];
    if (threadIdx.x == 255) blockSums[blockIdx.x] = tmp[255];
}

__global__ void scan_sums(int* __restrict__ blockSums, int nb) {
    __shared__ int tmp[1024];
    int i = threadIdx.x;
    tmp[i] = (i < nb) ? blockSums[i] : 0;
    __syncthreads();
    for (int off = 1; off < 1024; off <<= 1) {
        int t = (i >= off) ? tmp[i - off] : 0;
        __syncthreads();
        tmp[i] += t;
        __syncthreads();
    }
    if (i < nb) blockSums[i] = (i > 0) ? tmp[i - 1] : 0;
}

// out[i+1]=inclusive+blockOffset; start[i]=out[i+1]-cnt[i]; out[0]=0
__global__ void scan_finalize(const int* __restrict__ cnt, const int* __restrict__ blockSums,
                              int* __restrict__ outp, int* __restrict__ start, int n) {
    int i = blockIdx.x * 256 + threadIdx.x;
    if (i >= n) return;
    int inc = outp[i + 1] + blockSums[blockIdx.x];
    outp[i + 1] = inc;
    start[i] = inc - cnt[i];
    if (i == 0) outp[0] = 0;
}

// ---------- bucket binning: group edges by 128-row destination bucket ----------
__global__ void bucket_scatter(const int* __restrict__ esrc, const int* __restrict__ edst,
                               const float* __restrict__ evals, int* __restrict__ bcur,
                               int2* __restrict__ tmp, int E, int NB) {
    __shared__ int h[MAXNB];   // histogram, then per-bucket rank counters
    __shared__ int cb[MAXNB];  // per-bucket chunk base for this block
    for (int i = threadIdx.x; i < NB; i += 256) h[i] = 0;
    __syncthreads();
    int base = blockIdx.x * TILE;
    int end = base + TILE; if (end > E) end = E;
    for (int e = base + threadIdx.x; e < end; e += 256)
        atomicAdd(&h[edst[e] >> 7], 1);
    __syncthreads();
    for (int i = threadIdx.x; i < NB; i += 256) {
        int c = h[i];
        if (c) cb[i] = atomicAdd(&bcur[i], c);
        h[i] = 0;
    }
    __syncthreads();
    for (int e = base + threadIdx.x; e < end; e += 256) {
        int d = edst[e];
        int b = d >> 7;
        int r = atomicAdd(&h[b], 1);
        tmp[cb[b] + r] = make_int2(esrc[e] | ((d & 127) << 18), __float_as_int(evals[e]));
    }
}

// ---------- finalize: per-bucket node-level CSR + rank-sort, all in LDS ----------
__global__ void csr_from_buckets(const int* __restrict__ bptr, const int2* __restrict__ tmp,
                                 int2* __restrict__ pairs, int* __restrict__ rowptr,
                                 int N, int NB) {
    __shared__ int lcnt[BROWS];
    __shared__ int lofs[BROWS];   // inclusive scan of counts
    int b = blockIdx.x;
    int beg = bptr[b], end = bptr[b + 1];
    int rbase = b * BROWS;
    if (threadIdx.x < BROWS) lcnt[threadIdx.x] = 0;
    __syncthreads();
    for (int e = beg + threadIdx.x; e < end; e += 256)
        atomicAdd(&lcnt[(tmp[e].x >> 18)], 1);
    __syncthreads();
    if (threadIdx.x < BROWS) lofs[threadIdx.x] = lcnt[threadIdx.x];
    __syncthreads();
    for (int off = 1; off < BROWS; off <<= 1) {
        int t = (threadIdx.x < BROWS && threadIdx.x >= off) ? lofs[threadIdx.x - off] : 0;
        __syncthreads();
        if (threadIdx.x < BROWS) lofs[threadIdx.x] += t;
        __syncthreads();
    }
    if (threadIdx.x < BROWS) {
        int r = rbase + threadIdx.x;
        if (r < N) rowptr[r] = beg + (threadIdx.x ? lofs[threadIdx.x - 1] : 0);
    }
    if (b == NB - 1 && threadIdx.x == 0) rowptr[N] = end;
    if (threadIdx.x < BROWS) lcnt[threadIdx.x] = 0;   // reset for rank pass
    __syncthreads();
    for (int e = beg + threadIdx.x; e < end; e += 256) {
        int2 p = tmp[e];
        int dl = p.x >> 18;
        int r = atomicAdd(&lcnt[dl], 1);
        int basep = beg + (dl ? lofs[dl - 1] : 0);
        pairs[basep + r] = make_int2(p.x & 0x3FFFF, p.y);
    }
}

// ---------- fallback: node-level count + atomic CSR fill ----------
__global__ void count_deg(const int* __restrict__ dst, int* __restrict__ cnt, int E) {
    int e = blockIdx.x * blockDim.x + threadIdx.x;
    if (e >= E) return;
    atomicAdd(&cnt[dst[e]], 1);
}

__global__ void csr_fill(const int* __restrict__ src, const int* __restrict__ dst,
                         const float* __restrict__ vals, int* __restrict__ cursor,
                         int2* __restrict__ pairs, int E) {
    int e = blockIdx.x * blockDim.x + threadIdx.x;
    if (e >= E) return;
    int d = dst[e];
    int pos = atomicAdd(&cursor[d], 1);
    pairs[pos] = make_int2(src[e], __float_as_int(vals[e]));
}

// ---------- pull-mode SpMM, bf16 rows: one 16-lane group per destination row ----------
__global__ void spmm_pull_bf16(const int* __restrict__ rowptr, const int2* __restrict__ pairs,
                               const bf16_t* __restrict__ xb, bf16_t* __restrict__ yb, int Nrows) {
    long gid = (long)blockIdx.x * blockDim.x + threadIdx.x;
    int lane = (int)(gid & 15);
    long r = gid >> 4;
    if (r >= Nrows) return;
    int beg = rowptr[r];
    int end = rowptr[r + 1];
    float4 acc = make_float4(0.f, 0.f, 0.f, 0.f);
    int e = beg;
    for (; e + 3 < end; e += 4) {
        int2 p0 = pairs[e];
        int2 p1 = pairs[e + 1];
        int2 p2 = pairs[e + 2];
        int2 p3 = pairs[e + 3];
        ushort4 a0 = *(const ushort4*)(xb + (long)p0.x * DIM + lane * 4);
        ushort4 a1 = *(const ushort4*)(xb + (long)p1.x * DIM + lane * 4);
        ushort4 a2 = *(const ushort4*)(xb + (long)p2.x * DIM + lane * 4);
        ushort4 a3 = *(const ushort4*)(xb + (long)p3.x * DIM + lane * 4);
        float v0 = __int_as_float(p0.y), v1 = __int_as_float(p1.y);
        float v2 = __int_as_float(p2.y), v3 = __int_as_float(p3.y);
        acc.x += v0 * bf2f(a0.x) + v1 * bf2f(a1.x) + v2 * bf2f(a2.x) + v3 * bf2f(a3.x);
        acc.y += v0 * bf2f(a0.y) + v1 * bf2f(a1.y) + v2 * bf2f(a2.y) + v3 * bf2f(a3.y);
        acc.z += v0 * bf2f(a0.z) + v1 * bf2f(a1.z) + v2 * bf2f(a2.z) + v3 * bf2f(a3.z);
        acc.w += v0 * bf2f(a0.w) + v1 * bf2f(a1.w) + v2 * bf2f(a2.w) + v3 * bf2f(a3.w);
    }
    for (; e < end; ++e) {
        int2 p = pairs[e];
        float v = __int_as_float(p.y);
        ushort4 a = *(const ushort4*)(xb + (long)p.x * DIM + lane * 4);
        acc.x += v * bf2f(a.x); acc.y += v * bf2f(a.y);
        acc.z += v * bf2f(a.z); acc.w += v * bf2f(a.w);
    }
    ushort4 o;
    o.x = f2bf(acc.x); o.y = f2bf(acc.y); o.z = f2bf(acc.z); o.w = f2bf(acc.w);
    *(ushort4*)(yb + r * DIM + lane * 4) = o;
}

extern "C" void kernel_launch(void* const* d_in, const int* in_sizes, int n_in,
                              void* d_out, int out_size, void* d_ws, size_t ws_size,
                              hipStream_t stream) {
    const int*   users = (const int*)d_in[0];
    const int*   items = (const int*)d_in[1];
    const int*   esrc  = (const int*)d_in[2];
    const int*   edst  = (const int*)d_in[3];
    const float* evals = (const float*)d_in[4];
    const float* uemb  = (const float*)d_in[5];
    const float* iemb  = (const float*)d_in[6];

    const int B  = in_sizes[0];
    const int E  = in_sizes[2];
    const int nU = in_sizes[5] / DIM;
    const int nI = in_sizes[6] / DIM;
    const int N  = nU + nI;
    const int NB = (N + BROWS - 1) / BROWS;

    const int T = 256;
    float* gout = (float*)d_out;

    // ---- workspace layout ----
    char* p = (char*)d_ws;
    float*  accU  = (float*)p;          p += (size_t)B * DIM * 4;
    float*  accI  = (float*)p;          p += (size_t)B * DIM * 4;
    bf16_t* xbCur = (bf16_t*)p;         p += (size_t)N * DIM * 2;
    bf16_t* xbNxt = (bf16_t*)p;         p += (size_t)N * DIM * 2;
    int*    rowptr = (int*)p;           p += (size_t)(N + 1) * 4;
    int*    bcnt   = (int*)p;           p += (size_t)NB * 4;
    int*    bptr   = (int*)p;           p += (size_t)(NB + 1) * 4;
    int*    bcur   = (int*)p;           p += (size_t)NB * 4;
    int*    blockSums = (int*)p;        p += 1024 * 4;
    int*    cnt    = (int*)p;           p += (size_t)N * 4;   // fallback only
    int*    cursor = (int*)p;           p += (size_t)N * 4;   // fallback only
    p = (char*)(((size_t)p + 15) & ~(size_t)15);
    int2*   pairs  = (int2*)p;          p += (size_t)E * 8;
    size_t need_fb = (size_t)(p - (char*)d_ws);
    int2*   tmp    = (int2*)p;          p += (size_t)E * 8;
    size_t need_fast = (size_t)(p - (char*)d_ws);

    long total4 = (long)N * (DIM / 4);
    long nU4    = (long)nU * (DIM / 4);
    int gb = (int)(((long)B * 16 + T - 1) / T);
    int eb = (E + T - 1) / T;

    // layer-0 accumulators straight from fp32 embeddings
    hipMemsetAsync(accU, 0, (size_t)B * DIM * 2 * sizeof(float), stream);
    gather_accum_f32<<<gb, T, 0, stream>>>(users, uemb, accU, B);
    gather_accum_f32<<<gb, T, 0, stream>>>(items, iemb, accI, B);

    // bf16 node matrix
    build_xb<<<(int)((total4 + T - 1) / T), T, 0, stream>>>(
        (const float4*)uemb, (const float4*)iemb, (ushort4*)xbCur, nU4, total4);

    if (ws_size >= need_fast && NB <= MAXNB && N <= (1 << 18)) {
        // ---- bucket-level histogram + scan (NB counters; no N-wide atomics) ----
        int tb = (E + TILE - 1) / TILE;
        hipMemsetAsync(bcnt, 0, (size_t)NB * sizeof(int), stream);
        bucket_hist<<<tb, T, 0, stream>>>(edst, bcnt, E, NB);
        int nbB = (NB + 255) / 256;
        scan_block<<<nbB, 256, 0, stream>>>(bcnt, bptr + 1, blockSums, NB);
        scan_sums<<<1, 1024, 0, stream>>>(blockSums, nbB);
        scan_finalize<<<nbB, 256, 0, stream>>>(bcnt, blockSums, bptr, bcur, NB);
        // ---- group edges into buckets, then per-bucket CSR + rank-sort in LDS ----
        bucket_scatter<<<tb, T, 0, stream>>>(esrc, edst, evals, bcur, tmp, E, NB);
        csr_from_buckets<<<NB, T, 0, stream>>>(bptr, tmp, pairs, rowptr, N, NB);
    } else {
        // fallback: node-level count + scan + atomic fill
        hipMemsetAsync(cnt, 0, (size_t)N * sizeof(int), stream);
        count_deg<<<eb, T, 0, stream>>>(edst, cnt, E);
        int nbN = (N + 255) / 256;
        scan_block<<<nbN, 256, 0, stream>>>(cnt, rowptr + 1, blockSums, N);
        scan_sums<<<1, 1024, 0, stream>>>(blockSums, nbN);
        scan_finalize<<<nbN, 256, 0, stream>>>(cnt, blockSums, rowptr, cursor, N);
        csr_fill<<<eb, T, 0, stream>>>(esrc, edst, evals, cursor, pairs, E);
    }

    // ---- 3 propagation layers, bf16 storage, fp32 accumulation ----
    int pb = (int)(((long)N * 16 + T - 1) / T);
    for (int l = 0; l < 3; ++l) {
        spmm_pull_bf16<<<pb, T, 0, stream>>>(rowptr, pairs, xbCur, xbNxt, N);
        gather_accum_bf16<<<gb, T, 0, stream>>>(users, 0,  xbNxt, accU, B);
        gather_accum_bf16<<<gb, T, 0, stream>>>(items, nU, xbNxt, accI, B);
        bf16_t* t = xbCur; xbCur = xbNxt; xbNxt = t;
    }

    dot_pairs<<<gb, T, 0, stream>>>(accU, accI, gout, B);
}

// Round 6
// 1049.744 us; speedup vs baseline: 10.4069x; 1.0521x over previous
//
#include <hip/hip_runtime.h>

#define DIM 64
#define BROWS 512          // rows per bucket
#define LNB 512            // max buckets (N <= LNB*BROWS = 262144)
#define TILE 16384         // edges per binning block

typedef unsigned short bf16_t;

__device__ __forceinline__ float bf2f(unsigned short h) {
    return __uint_as_float(((unsigned)h) << 16);
}
__device__ __forceinline__ unsigned short f2bf(float f) {
    unsigned u = __float_as_uint(f);
    u += 0x7FFFu + ((u >> 16) & 1u);           // round-to-nearest-even
    return (unsigned short)(u >> 16);
}

// ---------- build bf16 node matrix from fp32 embeddings ----------
__global__ void build_xb(const float4* __restrict__ ue, const float4* __restrict__ ie,
                         ushort4* __restrict__ xb, long nU4, long total4) {
    long i = (long)blockIdx.x * blockDim.x + threadIdx.x;
    if (i >= total4) return;
    float4 v = (i < nU4) ? ue[i] : ie[i - nU4];
    ushort4 o;
    o.x = f2bf(v.x); o.y = f2bf(v.y); o.z = f2bf(v.z); o.w = f2bf(v.w);
    xb[i] = o;
}

// ---------- layer-0 gather (fp32 source) ----------
__global__ void gather_accum_f32(const int* __restrict__ idx, const float* __restrict__ x,
                                 float* __restrict__ acc, int B) {
    long gid = (long)blockIdx.x * blockDim.x + threadIdx.x;
    int lane = (int)(gid & 15);
    long b = gid >> 4;
    if (b >= B) return;
    long node = (long)idx[b];
    float4 r = ((const float4*)(x + node * DIM))[lane];
    float4* a = (float4*)(acc + b * DIM) + lane;
    float4 av = *a;
    av.x += r.x; av.y += r.y; av.z += r.z; av.w += r.w;
    *a = av;
}

// ---------- layer 1..3 gather (bf16 source) ----------
__global__ void gather_accum_bf16(const int* __restrict__ idx, int offset,
                                  const bf16_t* __restrict__ xb, float* __restrict__ acc, int B) {
    long gid = (long)blockIdx.x * blockDim.x + threadIdx.x;
    int lane = (int)(gid & 15);
    long b = gid >> 4;
    if (b >= B) return;
    long node = (long)idx[b] + offset;
    ushort4 r = *(const ushort4*)(xb + node * DIM + lane * 4);
    float4* a = (float4*)(acc + b * DIM) + lane;
    float4 av = *a;
    av.x += bf2f(r.x); av.y += bf2f(r.y); av.z += bf2f(r.z); av.w += bf2f(r.w);
    *a = av;
}

__global__ void dot_pairs(const float* __restrict__ aU, const float* __restrict__ aI,
                          float* __restrict__ out, int B) {
    long gid = (long)blockIdx.x * blockDim.x + threadIdx.x;
    int lane = (int)(gid & 15);
    long b = gid >> 4;
    if (b >= B) return;
    float4 u = ((const float4*)(aU + b * DIM))[lane];
    float4 v = ((const float4*)(aI + b * DIM))[lane];
    float s = u.x * v.x + u.y * v.y + u.z * v.z + u.w * v.w;
    s += __shfl_xor(s, 1);
    s += __shfl_xor(s, 2);
    s += __shfl_xor(s, 4);
    s += __shfl_xor(s, 8);
    if (lane == 0) out[b] = s * (1.0f / 16.0f);
}

// ---------- bucket histogram (LDS-aggregated; NB counters only) ----------
__global__ void bucket_hist(const int* __restrict__ edst, int* __restrict__ bcnt,
                            int E, int NB) {
    __shared__ int h[LNB];
    for (int i = threadIdx.x; i < NB; i += 256) h[i] = 0;
    __syncthreads();
    int base = blockIdx.x * TILE;
    int end = base + TILE; if (end > E) end = E;
    for (int e = base + threadIdx.x; e < end; e += 256)
        atomicAdd(&h[edst[e] >> 9], 1);
    __syncthreads();
    for (int i = threadIdx.x; i < NB; i += 256)
        if (h[i]) atomicAdd(&bcnt[i], h[i]);
}

// ---------- generic scan pipeline ----------
__global__ void scan_block(const int* __restrict__ cnt, int* __restrict__ out,
                           int* __restrict__ blockSums, int n) {
    __shared__ int tmp[256];
    int i = blockIdx.x * 256 + threadIdx.x;
    int v = (i < n) ? cnt[i] : 0;
    tmp[threadIdx.x] = v;
    __syncthreads();
    for (int off = 1; off < 256; off <<= 1) {
        int t = (threadIdx.x >= off) ? tmp[threadIdx.x - off] : 0;
        __syncthreads();
        tmp[threadIdx.x] += t;
        __syncthreads();
    }
    if (i < n) out[i] = tmp[threadIdx.x];
    if (threadIdx.x == 255) blockSums[blockIdx.x] = tmp[255];
}

__global__ void scan_sums(int* __restrict__ blockSums, int nb) {
    __shared__ int tmp[1024];
    int i = threadIdx.x;
    tmp[i] = (i < nb) ? blockSums[i] : 0;
    __syncthreads();
    for (int off = 1; off < 1024; off <<= 1) {
        int t = (i >= off) ? tmp[i - off] : 0;
        __syncthreads();
        tmp[i] += t;
        __syncthreads();
    }
    if (i < nb) blockSums[i] = (i > 0) ? tmp[i - 1] : 0;
}

// out[i+1]=inclusive+blockOffset; start[i]=out[i+1]-cnt[i]; out[0]=0
__global__ void scan_finalize(const int* __restrict__ cnt, const int* __restrict__ blockSums,
                              int* __restrict__ outp, int* __restrict__ start, int n) {
    int i = blockIdx.x * 256 + threadIdx.x;
    if (i >= n) return;
    int inc = outp[i + 1] + blockSums[blockIdx.x];
    outp[i + 1] = inc;
    start[i] = inc - cnt[i];
    if (i == 0) outp[0] = 0;
}

// ---------- bucket binning: group edges by 512-row destination bucket ----------
__global__ void bucket_scatter(const int* __restrict__ esrc, const int* __restrict__ edst,
                               const float* __restrict__ evals, int* __restrict__ bcur,
                               int2* __restrict__ tmp, int E, int NB) {
    __shared__ int h[LNB];    // histogram, then per-bucket rank counters
    __shared__ int cb[LNB];   // per-bucket chunk base for this block
    for (int i = threadIdx.x; i < NB; i += 256) h[i] = 0;
    __syncthreads();
    int base = blockIdx.x * TILE;
    int end = base + TILE; if (end > E) end = E;
    for (int e = base + threadIdx.x; e < end; e += 256)
        atomicAdd(&h[edst[e] >> 9], 1);
    __syncthreads();
    for (int i = threadIdx.x; i < NB; i += 256) {
        int c = h[i];
        if (c) cb[i] = atomicAdd(&bcur[i], c);
        h[i] = 0;
    }
    __syncthreads();
    for (int e = base + threadIdx.x; e < end; e += 256) {
        int d = edst[e];
        int b = d >> 9;
        int r = atomicAdd(&h[b], 1);
        tmp[cb[b] + r] = make_int2(esrc[e] | ((d & 511) << 18), __float_as_int(evals[e]));
    }
}

// ---------- finalize: per-bucket node-level CSR + rank-sort, all in LDS ----------
__global__ void csr_from_buckets(const int* __restrict__ bptr, const int2* __restrict__ tmp,
                                 int2* __restrict__ pairs, int* __restrict__ rowptr,
                                 int N, int NB) {
    __shared__ int lcnt[BROWS];
    __shared__ int lofs[BROWS];   // inclusive scan of counts
    const int T = 1024;
    int b = blockIdx.x;
    int beg = bptr[b], end = bptr[b + 1];
    int rbase = b * BROWS;
    if (threadIdx.x < BROWS) lcnt[threadIdx.x] = 0;
    __syncthreads();
    for (int e = beg + threadIdx.x; e < end; e += T)
        atomicAdd(&lcnt[(tmp[e].x >> 18)], 1);
    __syncthreads();
    if (threadIdx.x < BROWS) lofs[threadIdx.x] = lcnt[threadIdx.x];
    __syncthreads();
    for (int off = 1; off < BROWS; off <<= 1) {
        int t = (threadIdx.x < BROWS && threadIdx.x >= off) ? lofs[threadIdx.x - off] : 0;
        __syncthreads();
        if (threadIdx.x < BROWS) lofs[threadIdx.x] += t;
        __syncthreads();
    }
    if (threadIdx.x < BROWS) {
        int r = rbase + threadIdx.x;
        if (r < N) rowptr[r] = beg + (threadIdx.x ? lofs[threadIdx.x - 1] : 0);
    }
    if (b == NB - 1 && threadIdx.x == 0) rowptr[N] = end;
    if (threadIdx.x < BROWS) lcnt[threadIdx.x] = 0;   // reset for rank pass
    __syncthreads();
    for (int e = beg + threadIdx.x; e < end; e += T) {
        int2 p = tmp[e];
        int dl = p.x >> 18;
        int r = atomicAdd(&lcnt[dl], 1);
        int basep = beg + (dl ? lofs[dl - 1] : 0);
        pairs[basep + r] = make_int2(p.x & 0x3FFFF, p.y);
    }
}

// ---------- fallback: node-level count + atomic CSR fill ----------
__global__ void count_deg(const int* __restrict__ dst, int* __restrict__ cnt, int E) {
    int e = blockIdx.x * blockDim.x + threadIdx.x;
    if (e >= E) return;
    atomicAdd(&cnt[dst[e]], 1);
}

__global__ void csr_fill(const int* __restrict__ src, const int* __restrict__ dst,
                         const float* __restrict__ vals, int* __restrict__ cursor,
                         int2* __restrict__ pairs, int E) {
    int e = blockIdx.x * blockDim.x + threadIdx.x;
    if (e >= E) return;
    int d = dst[e];
    int pos = atomicAdd(&cursor[d], 1);
    pairs[pos] = make_int2(src[e], __float_as_int(vals[e]));
}

// ---------- pull-mode SpMM, bf16 rows: one 16-lane group per destination row ----------
__global__ void spmm_pull_bf16(const int* __restrict__ rowptr, const int2* __restrict__ pairs,
                               const bf16_t* __restrict__ xb, bf16_t* __restrict__ yb, int Nrows) {
    long gid = (long)blockIdx.x * blockDim.x + threadIdx.x;
    int lane = (int)(gid & 15);
    long r = gid >> 4;
    if (r >= Nrows) return;
    int beg = rowptr[r];
    int end = rowptr[r + 1];
    float4 acc = make_float4(0.f, 0.f, 0.f, 0.f);
    int e = beg;
    for (; e + 3 < end; e += 4) {
        int2 p0 = pairs[e];
        int2 p1 = pairs[e + 1];
        int2 p2 = pairs[e + 2];
        int2 p3 = pairs[e + 3];
        ushort4 a0 = *(const ushort4*)(xb + (long)p0.x * DIM + lane * 4);
        ushort4 a1 = *(const ushort4*)(xb + (long)p1.x * DIM + lane * 4);
        ushort4 a2 = *(const ushort4*)(xb + (long)p2.x * DIM + lane * 4);
        ushort4 a3 = *(const ushort4*)(xb + (long)p3.x * DIM + lane * 4);
        float v0 = __int_as_float(p0.y), v1 = __int_as_float(p1.y);
        float v2 = __int_as_float(p2.y), v3 = __int_as_float(p3.y);
        acc.x += v0 * bf2f(a0.x) + v1 * bf2f(a1.x) + v2 * bf2f(a2.x) + v3 * bf2f(a3.x);
        acc.y += v0 * bf2f(a0.y) + v1 * bf2f(a1.y) + v2 * bf2f(a2.y) + v3 * bf2f(a3.y);
        acc.z += v0 * bf2f(a0.z) + v1 * bf2f(a1.z) + v2 * bf2f(a2.z) + v3 * bf2f(a3.z);
        acc.w += v0 * bf2f(a0.w) + v1 * bf2f(a1.w) + v2 * bf2f(a2.w) + v3 * bf2f(a3.w);
    }
    for (; e < end; ++e) {
        int2 p = pairs[e];
        float v = __int_as_float(p.y);
        ushort4 a = *(const ushort4*)(xb + (long)p.x * DIM + lane * 4);
        acc.x += v * bf2f(a.x); acc.y += v * bf2f(a.y);
        acc.z += v * bf2f(a.z); acc.w += v * bf2f(a.w);
    }
    ushort4 o;
    o.x = f2bf(acc.x); o.y = f2bf(acc.y); o.z = f2bf(acc.z); o.w = f2bf(acc.w);
    *(ushort4*)(yb + r * DIM + lane * 4) = o;
}

extern "C" void kernel_launch(void* const* d_in, const int* in_sizes, int n_in,
                              void* d_out, int out_size, void* d_ws, size_t ws_size,
                              hipStream_t stream) {
    const int*   users = (const int*)d_in[0];
    const int*   items = (const int*)d_in[1];
    const int*   esrc  = (const int*)d_in[2];
    const int*   edst  = (const int*)d_in[3];
    const float* evals = (const float*)d_in[4];
    const float* uemb  = (const float*)d_in[5];
    const float* iemb  = (const float*)d_in[6];

    const int B  = in_sizes[0];
    const int E  = in_sizes[2];
    const int nU = in_sizes[5] / DIM;
    const int nI = in_sizes[6] / DIM;
    const int N  = nU + nI;
    const int NB = (N + BROWS - 1) / BROWS;

    const int T = 256;
    float* gout = (float*)d_out;

    // ---- workspace layout ----
    char* p = (char*)d_ws;
    float*  accU  = (float*)p;          p += (size_t)B * DIM * 4;
    float*  accI  = (float*)p;          p += (size_t)B * DIM * 4;
    bf16_t* xbCur = (bf16_t*)p;         p += (size_t)N * DIM * 2;
    bf16_t* xbNxt = (bf16_t*)p;         p += (size_t)N * DIM * 2;
    int*    rowptr = (int*)p;           p += (size_t)(N + 1) * 4;
    int*    bcnt   = (int*)p;           p += (size_t)NB * 4;
    int*    bptr   = (int*)p;           p += (size_t)(NB + 1) * 4;
    int*    bcur   = (int*)p;           p += (size_t)NB * 4;
    int*    blockSums = (int*)p;        p += 1024 * 4;
    int*    cnt    = (int*)p;           p += (size_t)N * 4;   // fallback only
    int*    cursor = (int*)p;           p += (size_t)N * 4;   // fallback only
    p = (char*)(((size_t)p + 15) & ~(size_t)15);
    int2*   pairs  = (int2*)p;          p += (size_t)E * 8;
    size_t need_fb = (size_t)(p - (char*)d_ws);
    int2*   tmp    = (int2*)p;          p += (size_t)E * 8;
    size_t need_fast = (size_t)(p - (char*)d_ws);

    long total4 = (long)N * (DIM / 4);
    long nU4    = (long)nU * (DIM / 4);
    int gb = (int)(((long)B * 16 + T - 1) / T);
    int eb = (E + T - 1) / T;

    // layer-0 accumulators straight from fp32 embeddings
    hipMemsetAsync(accU, 0, (size_t)B * DIM * 2 * sizeof(float), stream);
    gather_accum_f32<<<gb, T, 0, stream>>>(users, uemb, accU, B);
    gather_accum_f32<<<gb, T, 0, stream>>>(items, iemb, accI, B);

    // bf16 node matrix
    build_xb<<<(int)((total4 + T - 1) / T), T, 0, stream>>>(
        (const float4*)uemb, (const float4*)iemb, (ushort4*)xbCur, nU4, total4);

    if (ws_size >= need_fast && NB <= LNB && N <= (1 << 18)) {
        // ---- bucket-level histogram + scan (NB counters; no N-wide atomics) ----
        int tb = (E + TILE - 1) / TILE;
        hipMemsetAsync(bcnt, 0, (size_t)NB * sizeof(int), stream);
        bucket_hist<<<tb, T, 0, stream>>>(edst, bcnt, E, NB);
        int nbB = (NB + 255) / 256;
        scan_block<<<nbB, 256, 0, stream>>>(bcnt, bptr + 1, blockSums, NB);
        scan_sums<<<1, 1024, 0, stream>>>(blockSums, nbB);
        scan_finalize<<<nbB, 256, 0, stream>>>(bcnt, blockSums, bptr, bcur, NB);
        // ---- group edges into buckets, then per-bucket CSR + rank-sort in LDS ----
        bucket_scatter<<<tb, T, 0, stream>>>(esrc, edst, evals, bcur, tmp, E, NB);
        csr_from_buckets<<<NB, 1024, 0, stream>>>(bptr, tmp, pairs, rowptr, N, NB);
    } else {
        // fallback: node-level count + scan + atomic fill
        hipMemsetAsync(cnt, 0, (size_t)N * sizeof(int), stream);
        count_deg<<<eb, T, 0, stream>>>(edst, cnt, E);
        int nbN = (N + 255) / 256;
        scan_block<<<nbN, 256, 0, stream>>>(cnt, rowptr + 1, blockSums, N);
        scan_sums<<<1, 1024, 0, stream>>>(blockSums, nbN);
        scan_finalize<<<nbN, 256, 0, stream>>>(cnt, blockSums, rowptr, cursor, N);
        csr_fill<<<eb, T, 0, stream>>>(esrc, edst, evals, cursor, pairs, E);
    }

    // ---- 3 propagation layers, bf16 storage, fp32 accumulation ----
    int pb = (int)(((long)N * 16 + T - 1) / T);
    for (int l = 0; l < 3; ++l) {
        spmm_pull_bf16<<<pb, T, 0, stream>>>(rowptr, pairs, xbCur, xbNxt, N);
        gather_accum_bf16<<<gb, T, 0, stream>>>(users, 0,  xbNxt, accU, B);
        gather_accum_bf16<<<gb, T, 0, stream>>>(items, nU, xbNxt, accI, B);
        bf16_t* t = xbCur; xbCur = xbNxt; xbNxt = t;
    }

    dot_pairs<<<gb, T, 0, stream>>>(accU, accI, gout, B);
}